// Round 6
// baseline (466.498 us; speedup 1.0000x reference)
//
#include <hip/hip_runtime.h>

#define Bn 128
#define Vn 128000
#define NBLK 512
#define MT 256
#define QLEN 32000           // Vn / 4 blocks per row
#define QV4 8000
#define NB1 512              // L1 bins: K>>21
#define NB2 512              // L2 sub-bins: K bits [20:12]
#define CAP 512
#define FMINV -3.4028234663852886e38f
#define FOUT  -3.3895313892515355e38f   // max-finite bf16; masked outputs

// ---- ws arena ----
#define OFF_CNT    0u
#define OFF_ROWS   512u
#define OFF_SLICEM 19968u
#define OFF_SLICEZ 22016u
#define OFF_L1S    32768u
#define OFF_L1C    557056u
#define OFF_L2S    819200u
#define OFF_L2C    3440640u
#define OFF_LCNT   4751360u
#define OFF_LISTS  4755456u
#define ZERO_BYTES 4755456u

struct RowWS {
  float Zf, S2f, t4, lpTok;
  unsigned thrBits; int q4mode, token; unsigned v0;
  int i0; unsigned v2; int i2; unsigned pad;
  unsigned cutBin[5], cutPre[5], Cbef[5], pad2;
  double Sbef[5];
};

__device__ __forceinline__ unsigned aldU(const unsigned* p){ return __hip_atomic_load((unsigned*)p, __ATOMIC_RELAXED, __HIP_MEMORY_SCOPE_AGENT); }
__device__ __forceinline__ int aldI(const int* p){ return __hip_atomic_load((int*)p, __ATOMIC_RELAXED, __HIP_MEMORY_SCOPE_AGENT); }
__device__ __forceinline__ float aldF(const float* p){ return __hip_atomic_load((float*)p, __ATOMIC_RELAXED, __HIP_MEMORY_SCOPE_AGENT); }
__device__ __forceinline__ double aldD(const double* p){ return __hip_atomic_load((double*)p, __ATOMIC_RELAXED, __HIP_MEMORY_SCOPE_AGENT); }
__device__ __forceinline__ unsigned long long aldL(const unsigned long long* p){ return __hip_atomic_load((unsigned long long*)p, __ATOMIC_RELAXED, __HIP_MEMORY_SCOPE_AGENT); }
__device__ __forceinline__ void astU(unsigned* p, unsigned v){ __hip_atomic_store(p, v, __ATOMIC_RELAXED, __HIP_MEMORY_SCOPE_AGENT); }
__device__ __forceinline__ void astI(int* p, int v){ __hip_atomic_store(p, v, __ATOMIC_RELAXED, __HIP_MEMORY_SCOPE_AGENT); }
__device__ __forceinline__ void astF(float* p, float v){ __hip_atomic_store(p, v, __ATOMIC_RELAXED, __HIP_MEMORY_SCOPE_AGENT); }
__device__ __forceinline__ void astD(double* p, double v){ __hip_atomic_store(p, v, __ATOMIC_RELAXED, __HIP_MEMORY_SCOPE_AGENT); }
__device__ __forceinline__ void astL(unsigned long long* p, unsigned long long v){ __hip_atomic_store(p, v, __ATOMIC_RELAXED, __HIP_MEMORY_SCOPE_AGENT); }

__device__ __forceinline__ void gridbar(unsigned* cnt, int idx){
  asm volatile("s_waitcnt vmcnt(0) lgkmcnt(0)" ::: "memory");
  __syncthreads();
  if (threadIdx.x == 0){
    __hip_atomic_fetch_add(&cnt[idx], 1u, __ATOMIC_RELAXED, __HIP_MEMORY_SCOPE_AGENT);
    unsigned v;
    do { __builtin_amdgcn_s_sleep(4);
         v = __hip_atomic_load(&cnt[idx], __ATOMIC_RELAXED, __HIP_MEMORY_SCOPE_AGENT);
    } while (v < (unsigned)NBLK);
  }
  __syncthreads();
}

// suffix scan over 512 bins with 256 threads (each owns t and t+256); sS/sC[512] must be 0
__device__ __forceinline__ void scan512(double* sS, unsigned* sC){
  int t = threadIdx.x;
  for (int off = 1; off < 512; off <<= 1){
    double a1 = sS[t], b1 = (t+off < 512) ? sS[t+off] : 0.0;
    double a2 = sS[t+256], b2 = (t+256+off < 512) ? sS[t+256+off] : 0.0;
    unsigned c1 = sC[t], d1 = (t+off < 512) ? sC[t+off] : 0u;
    unsigned c2 = sC[t+256], d2 = (t+256+off < 512) ? sC[t+256+off] : 0u;
    __syncthreads();
    sS[t] = a1 + b1; sS[t+256] = a2 + b2;
    sC[t] = c1 + d1; sC[t+256] = c2 + d2;
    __syncthreads();
  }
}

__global__ __launch_bounds__(MT, 2) void mega(
    const float* __restrict__ logits, const float* __restrict__ temps,
    const int* __restrict__ top_ks, const float* __restrict__ top_ps,
    const float* __restrict__ top_ps2, const float* __restrict__ min_ps,
    const float* __restrict__ uarr, char* __restrict__ ws,
    float* __restrict__ outTok, float* __restrict__ outLp, float* __restrict__ outNtlp)
{
  __shared__ __align__(16) char smem[24832];
  __shared__ float sRedF[4]; __shared__ double sRedD[4];
  __shared__ float sA, sZf, sS2f;
  __shared__ int mx0, mx1, mx2, mnz, sMode, sI2;
  __shared__ unsigned sB[4], sV2, sT4p, snapC, snapCut, snapThr;
  __shared__ double snapS, sT4d;

  unsigned* cnt = (unsigned*)(ws + OFF_CNT);
  RowWS* rows = (RowWS*)(ws + OFF_ROWS);
  float* sliceM = (float*)(ws + OFF_SLICEM);
  double* sliceZ = (double*)(ws + OFF_SLICEZ);
  double* L1S = (double*)(ws + OFF_L1S);
  unsigned* L1C = (unsigned*)(ws + OFF_L1C);
  double* L2S = (double*)(ws + OFF_L2S);
  unsigned* L2C = (unsigned*)(ws + OFF_L2C);
  unsigned* lcnt = (unsigned*)(ws + OFF_LCNT);
  unsigned long long* lists = (unsigned long long*)(ws + OFF_LISTS);
  unsigned* Kc = (unsigned*)outLp;

  const int g = blockIdx.x, tid = threadIdx.x;
  const int b = g >> 2, qq = g & 3;
  const float T = temps[b];
  const size_t base = (size_t)b*Vn + (size_t)qq*QLEN;
  const float4* l4 = (const float4*)(logits + base);
  uint4* K4 = (uint4*)(Kc + base);

  // ---------- ph1: quarter-row max + exp-sum ----------
  {
    float m = -3.4e38f;
    for (int j = tid; j < QV4; j += MT){
      float4 v = l4[j];
      m = fmaxf(m, fmaxf(fmaxf(v.x, v.y), fmaxf(v.z, v.w)));
    }
    #pragma unroll
    for (int o = 32; o; o >>= 1) m = fmaxf(m, __shfl_down(m, o));
    if ((tid & 63) == 0) sRedF[tid >> 6] = m;
    __syncthreads();
    if (tid == 0){ float mm = sRedF[0]; for (int w = 1; w < 4; ++w) mm = fmaxf(mm, sRedF[w]); sA = mm; }
    __syncthreads();
    float a = sA / T;
    double z = 0.0;
    for (int j = tid; j < QV4; j += MT){
      float4 v = l4[j];
      z += (double)expf(v.x/T - a) + (double)expf(v.y/T - a)
         + (double)expf(v.z/T - a) + (double)expf(v.w/T - a);
    }
    #pragma unroll
    for (int o = 32; o; o >>= 1) z += __shfl_down(z, o);
    if ((tid & 63) == 0) sRedD[tid >> 6] = z;
    __syncthreads();
    if (tid == 0){
      double zz = 0.0; for (int w = 0; w < 4; ++w) zz += sRedD[w];
      astF(&sliceM[b*4 + qq], sA);
      astD(&sliceZ[b*4 + qq], zz);
    }
  }
  gridbar(cnt, 0);

  // ---------- ph2: combine + L1 hist + Kc write ----------
  {
    if (tid == 0){
      float m0 = aldF(&sliceM[b*4]), m1 = aldF(&sliceM[b*4+1]);
      float m2 = aldF(&sliceM[b*4+2]), m3 = aldF(&sliceM[b*4+3]);
      float M = fmaxf(fmaxf(m0, m1), fmaxf(m2, m3));
      float A = M / T;
      double Z = aldD(&sliceZ[b*4])   * exp((double)(m0/T) - (double)A)
               + aldD(&sliceZ[b*4+1]) * exp((double)(m1/T) - (double)A)
               + aldD(&sliceZ[b*4+2]) * exp((double)(m2/T) - (double)A)
               + aldD(&sliceZ[b*4+3]) * exp((double)(m3/T) - (double)A);
      sA = A; sZf = (float)Z;
      if (qq == 0) astF(&rows[b].Zf, (float)Z);
    }
    double* hS = (double*)smem;               // 4*512 f64
    unsigned* hC = (unsigned*)(smem + 16384); // 4*512 u32
    for (int i = tid; i < 4*NB1; i += MT){ hS[i] = 0.0; hC[i] = 0u; }
    __syncthreads();
    float A = sA, Zf = sZf;
    int cp = (tid >> 6) & 3;
    for (int j = tid; j < QV4; j += MT){
      float4 v = l4[j];
      uint4 kk;
      float p0 = expf(v.x/T - A) / Zf; kk.x = __float_as_uint(p0);
      float p1 = expf(v.y/T - A) / Zf; kk.y = __float_as_uint(p1);
      float p2 = expf(v.z/T - A) / Zf; kk.z = __float_as_uint(p2);
      float p3 = expf(v.w/T - A) / Zf; kk.w = __float_as_uint(p3);
      unsigned b0 = min(kk.x >> 21, NB1-1u), b1 = min(kk.y >> 21, NB1-1u);
      unsigned b2 = min(kk.z >> 21, NB1-1u), b3 = min(kk.w >> 21, NB1-1u);
      unsafeAtomicAdd(&hS[cp*NB1 + b0], (double)p0); atomicAdd(&hC[cp*NB1 + b0], 1u);
      unsafeAtomicAdd(&hS[cp*NB1 + b1], (double)p1); atomicAdd(&hC[cp*NB1 + b1], 1u);
      unsafeAtomicAdd(&hS[cp*NB1 + b2], (double)p2); atomicAdd(&hC[cp*NB1 + b2], 1u);
      unsafeAtomicAdd(&hS[cp*NB1 + b3], (double)p3); atomicAdd(&hC[cp*NB1 + b3], 1u);
      K4[j] = kk;
    }
    __syncthreads();
    for (int bin = tid; bin < NB1; bin += MT){
      unsigned c = hC[bin] + hC[NB1+bin] + hC[2*NB1+bin] + hC[3*NB1+bin];
      if (c){
        double s = hS[bin] + hS[NB1+bin] + hS[2*NB1+bin] + hS[3*NB1+bin];
        unsafeAtomicAdd(&L1S[(size_t)b*NB1 + bin], s);
        atomicAdd(&L1C[(size_t)b*NB1 + bin], c);
      }
    }
  }
  gridbar(cnt, 1);

  // ---------- ph3: L1 walk (blocks 0..127) ----------
  if (g < Bn){
    int r = g;
    double* sS = (double*)smem;                 // 513
    unsigned* sC = (unsigned*)(smem + 4104);    // 513
    if (tid == 0){ sS[512] = 0.0; sC[512] = 0u; mx0 = -1; mx1 = -1; mx2 = -1; mnz = NB1; }
    unsigned cA = aldU(&L1C[(size_t)r*NB1 + tid]);
    unsigned cB = aldU(&L1C[(size_t)r*NB1 + tid + 256]);
    sS[tid] = aldD(&L1S[(size_t)r*NB1 + tid]);
    sS[tid+256] = aldD(&L1S[(size_t)r*NB1 + tid + 256]);
    sC[tid] = cA; sC[tid+256] = cB;
    __syncthreads();
    scan512(sS, sC);
    RowWS& R = rows[r];
    float Zf = aldF(&R.Zf);
    float thr = (1.0f / Zf) * min_ps[r];
    unsigned thrBits = __float_as_uint(thr);
    int thrBin = (int)(thrBits >> 21); if (thrBin > NB1-1) thrBin = NB1-1;
    unsigned k = (unsigned)top_ks[r];
    double tauP = (double)top_ps[r], tauP2 = (double)top_ps2[r];
    if (cA){
      if (sC[tid] >= k)    atomicMax(&mx0, tid);
      if (sS[tid] > tauP ) atomicMax(&mx1, tid);
      if (sS[tid] > tauP2) atomicMax(&mx2, tid);
      atomicMin(&mnz, tid);
    }
    if (cB){
      int t2 = tid + 256;
      if (sC[t2] >= k)    atomicMax(&mx0, t2);
      if (sS[t2] > tauP ) atomicMax(&mx1, t2);
      if (sS[t2] > tauP2) atomicMax(&mx2, t2);
      atomicMin(&mnz, t2);
    }
    __syncthreads();
    if (tid == 0) astU(&R.thrBits, thrBits);
    int w0 = mx0, w1 = (mx1 >= 0) ? mx1 : mnz, w2 = (mx2 >= 0) ? mx2 : mnz;
    #pragma unroll
    for (int h = 0; h < 2; ++h){
      int i = tid + h*256;
      if (i == thrBin){ astU(&R.cutBin[3], (unsigned)i); astU(&R.Cbef[3], sC[i+1]); astD(&R.Sbef[3], sS[i+1]); }
      if (i == w0){ astU(&R.cutBin[0], (unsigned)i); astU(&R.Cbef[0], sC[i+1]); astD(&R.Sbef[0], sS[i+1]); }
      if (i == w1){ astU(&R.cutBin[1], (unsigned)i); astU(&R.Cbef[1], sC[i+1]); astD(&R.Sbef[1], sS[i+1]); }
      if (i == w2){ astU(&R.cutBin[2], (unsigned)i); astU(&R.Cbef[2], sC[i+1]); astD(&R.Sbef[2], sS[i+1]); }
    }
  }
  gridbar(cnt, 2);

  // ---------- ph4: L2 hist q0..q3 ----------
  {
    if (tid == 0){
      sB[0] = aldU(&rows[b].cutBin[0]); sB[1] = aldU(&rows[b].cutBin[1]);
      sB[2] = aldU(&rows[b].cutBin[2]); sB[3] = aldU(&rows[b].cutBin[3]);
    }
    double* hS = (double*)smem;
    unsigned* hC = (unsigned*)(smem + 16384);
    for (int i = tid; i < 4*NB2; i += MT){ hS[i] = 0.0; hC[i] = 0u; }
    __syncthreads();
    unsigned tb0 = sB[0], tb1 = sB[1], tb2 = sB[2], tb3 = sB[3];
    for (int j = tid; j < QV4; j += MT){
      uint4 kk = K4[j];
      #pragma unroll
      for (int c = 0; c < 4; ++c){
        unsigned K = (c==0)?kk.x:(c==1)?kk.y:(c==2)?kk.z:kk.w;
        unsigned bin = K >> 21, sub = (K >> 12) & (NB2-1);
        double p = (double)__uint_as_float(K);
        if (bin == tb0){ unsafeAtomicAdd(&hS[0*NB2+sub], p); atomicAdd(&hC[0*NB2+sub], 1u); }
        if (bin == tb1){ unsafeAtomicAdd(&hS[1*NB2+sub], p); atomicAdd(&hC[1*NB2+sub], 1u); }
        if (bin == tb2){ unsafeAtomicAdd(&hS[2*NB2+sub], p); atomicAdd(&hC[2*NB2+sub], 1u); }
        if (bin == tb3){ unsafeAtomicAdd(&hS[3*NB2+sub], p); atomicAdd(&hC[3*NB2+sub], 1u); }
      }
    }
    __syncthreads();
    for (int i = tid; i < 4*NB2; i += MT){
      if (hC[i]){
        unsafeAtomicAdd(&L2S[((size_t)b*5)*NB2 + i], hS[i]);
        atomicAdd(&L2C[((size_t)b*5)*NB2 + i], hC[i]);
      }
    }
  }
  gridbar(cnt, 3);

  // ---------- ph5: L2 walk, block = (row, q) ----------
  {
    int r = b, q = qq;
    RowWS& R = rows[r];
    double* sS = (double*)smem;
    unsigned* sC = (unsigned*)(smem + 4104);
    if (tid == 0){
      sS[512] = 0.0; sC[512] = 0u; mx0 = -1; mnz = NB2;
      snapC = aldU(&R.Cbef[q]); snapS = aldD(&R.Sbef[q]);
      snapCut = aldU(&R.cutBin[q]); snapThr = aldU(&R.thrBits);
    }
    unsigned cA = aldU(&L2C[((size_t)r*5+q)*NB2 + tid]);
    unsigned cB = aldU(&L2C[((size_t)r*5+q)*NB2 + tid + 256]);
    sS[tid] = aldD(&L2S[((size_t)r*5+q)*NB2 + tid]);
    sS[tid+256] = aldD(&L2S[((size_t)r*5+q)*NB2 + tid + 256]);
    sC[tid] = cA; sC[tid+256] = cB;
    __syncthreads();
    scan512(sS, sC);
    unsigned baseC = snapC, cutBin = snapCut; double baseS = snapS;
    if (q == 3){
      int thrSub = (int)((snapThr >> 12) & (NB2-1));
      #pragma unroll
      for (int h = 0; h < 2; ++h){
        int i = tid + h*256;
        if (i == thrSub){
          astU(&R.cutPre[3], (cutBin << 9) | (unsigned)i);
          astU(&R.Cbef[3], baseC + sC[i+1]); astD(&R.Sbef[3], baseS + sS[i+1]);
        }
      }
    } else {
      unsigned k = (unsigned)top_ks[r];
      double tau = (q == 1) ? (double)top_ps[r] : (double)top_ps2[r];
      if (cA){
        if (q == 0){ if (baseC + sC[tid] >= k) atomicMax(&mx0, tid); }
        else       { if (baseS + sS[tid] > tau) atomicMax(&mx0, tid); }
        atomicMin(&mnz, tid);
      }
      if (cB){
        int t2 = tid + 256;
        if (q == 0){ if (baseC + sC[t2] >= k) atomicMax(&mx0, t2); }
        else       { if (baseS + sS[t2] > tau) atomicMax(&mx0, t2); }
        atomicMin(&mnz, t2);
      }
      __syncthreads();
      int w = (mx0 >= 0) ? mx0 : mnz;
      #pragma unroll
      for (int h = 0; h < 2; ++h){
        int i = tid + h*256;
        if (i == w){
          astU(&R.cutPre[q], (cutBin << 9) | (unsigned)i);
          astU(&R.Cbef[q], baseC + sC[i+1]); astD(&R.Sbef[q], baseS + sS[i+1]);
        }
      }
    }
  }
  gridbar(cnt, 4);

  // ---------- ph6: collect boundary candidates q0..q3 ----------
  {
    if (tid == 0){
      sB[0] = aldU(&rows[b].cutPre[0]); sB[1] = aldU(&rows[b].cutPre[1]);
      sB[2] = aldU(&rows[b].cutPre[2]); sB[3] = aldU(&rows[b].cutPre[3]);
    }
    __syncthreads();
    unsigned t0 = sB[0], t1 = sB[1], t2 = sB[2], t3 = sB[3];
    int ibase = qq*QLEN;
    for (int j = tid; j < QV4; j += MT){
      uint4 kk = K4[j];
      #pragma unroll
      for (int c = 0; c < 4; ++c){
        unsigned K = (c==0)?kk.x:(c==1)?kk.y:(c==2)?kk.z:kk.w;
        unsigned pre = K >> 12;
        if (pre != t0 && pre != t1 && pre != t2 && pre != t3) continue;
        int i = ibase + j*4 + c;
        unsigned long long e = (((unsigned long long)(~K)) << 32) | (unsigned)i;
        if (pre == t0){ unsigned pos = atomicAdd(&lcnt[b*8+0], 1u); if (pos < CAP) astL(&lists[((size_t)b*5+0)*CAP+pos], e); }
        if (pre == t1){ unsigned pos = atomicAdd(&lcnt[b*8+1], 1u); if (pos < CAP) astL(&lists[((size_t)b*5+1)*CAP+pos], e); }
        if (pre == t2){ unsigned pos = atomicAdd(&lcnt[b*8+2], 1u); if (pos < CAP) astL(&lists[((size_t)b*5+2)*CAP+pos], e); }
        if (pre == t3){ unsigned pos = atomicAdd(&lcnt[b*8+3], 1u); if (pos < CAP) astL(&lists[((size_t)b*5+3)*CAP+pos], e); }
      }
    }
  }
  gridbar(cnt, 5);

  // ---------- ph7: resolve (blocks 0..127) + q4 L1 walk ----------
  if (g < Bn){
    int r = g;
    RowWS& R = rows[r];
    double* sS = (double*)smem;
    unsigned* sC = (unsigned*)(smem + 4104);
    unsigned long long* Ls = (unsigned long long*)(smem + 8192);  // 4*CAP
    int nq[4];
    for (int q = 0; q < 4; ++q){
      int n = (int)aldU(&lcnt[r*8+q]); if (n > CAP) n = CAP; nq[q] = n;
      for (int j = tid; j < n; j += MT) Ls[q*CAP+j] = aldL(&lists[((size_t)r*5+q)*CAP + j]);
    }
    if (tid == 0){ sS[512] = 0.0; sC[512] = 0u; mx0 = -1; }
    unsigned cA = aldU(&L1C[(size_t)r*NB1 + tid]);
    unsigned cB = aldU(&L1C[(size_t)r*NB1 + tid + 256]);
    sS[tid] = aldD(&L1S[(size_t)r*NB1 + tid]);
    sS[tid+256] = aldD(&L1S[(size_t)r*NB1 + tid + 256]);
    sC[tid] = cA; sC[tid+256] = cB;
    __syncthreads();
    scan512(sS, sC);
    if (tid == 0){
      int k = top_ks[r];
      double tauP = (double)top_ps[r], tauP2 = (double)top_ps2[r];
      unsigned thrB = aldU(&R.thrBits);
      unsigned vS[4]; int iS[4]; double sk[4];
      for (int q = 0; q < 4; ++q){
        int n = nq[q];
        unsigned long long* L = &Ls[q*CAP];
        for (int i2 = 1; i2 < n; ++i2){
          unsigned long long key = L[i2]; int j = i2-1;
          while (j >= 0 && L[j] > key){ L[j+1] = L[j]; --j; }
          L[j+1] = key;
        }
        double S = aldD(&R.Sbef[q]);
        if (q == 0){
          if (n > 0){
            int mm = k - (int)aldU(&R.Cbef[0]); if (mm < 1) mm = 1; if (mm > n) mm = n;
            for (int j = 0; j < mm; ++j){ unsigned K = ~(unsigned)(L[j] >> 32); S += (double)__uint_as_float(K); }
            unsigned long long e = L[mm-1];
            vS[0] = ~(unsigned)(e >> 32); iS[0] = (int)(unsigned)(e & 0xFFFFFFFFu); sk[0] = S;
          } else { vS[0] = 0u; iS[0] = 0x7FFFFFFF; sk[0] = S; }
        } else if (q < 3){
          double tau = (q == 1) ? tauP : tauP2;
          int last = -1;
          for (int j = 0; j < n; ++j){
            if (S > tau) break;
            unsigned K = ~(unsigned)(L[j] >> 32);
            S += (double)__uint_as_float(K); last = j;
          }
          if (n > 0){
            int pick = (last < 0) ? 0 : last;
            unsigned long long e = L[pick];
            vS[q] = ~(unsigned)(e >> 32); iS[q] = (int)(unsigned)(e & 0xFFFFFFFFu); sk[q] = S;
          } else { vS[q] = 0u; iS[q] = 0x7FFFFFFF; sk[q] = S; }
        } else {
          for (int j = 0; j < n; ++j){
            unsigned K = ~(unsigned)(L[j] >> 32);
            if (K < thrB) break;
            S += (double)__uint_as_float(K);
          }
          vS[3] = thrB; iS[3] = 0x7FFFFFFF; sk[3] = S;
        }
      }
      unsigned v0 = vS[0]; int i0 = iS[0]; double tot = sk[0];
      if (vS[1] > v0 || (vS[1] == v0 && iS[1] < i0)){ v0 = vS[1]; i0 = iS[1]; tot = sk[1]; }
      if (vS[3] > v0 || (vS[3] == v0 && iS[3] < i0)){ v0 = vS[3]; i0 = iS[3]; tot = sk[3]; }
      astU(&R.v0, v0); astI(&R.i0, i0);
      astU(&R.v2, vS[2]); astI(&R.i2, iS[2]); astF(&R.S2f, (float)sk[2]);
      float t4 = uarr[r] * (float)tot;
      astF(&R.t4, t4);
      sT4d = (double)t4;
      sMode = i0;  // stash i0 for fallback below
    }
    __syncthreads();
    double t4d = sT4d;
    if (cA && sS[tid] >= t4d) atomicMax(&mx0, tid);
    if (cB && sS[tid+256] >= t4d) atomicMax(&mx0, tid+256);
    __syncthreads();
    int w = mx0;
    if (w < 0){
      if (tid == 0){ astI(&R.q4mode, 2); astI(&R.token, sMode); }
    } else {
      if (tid == 0) astI(&R.q4mode, 0);
      #pragma unroll
      for (int h = 0; h < 2; ++h){
        int i = tid + h*256;
        if (i == w){ astU(&R.cutBin[4], (unsigned)i); astU(&R.Cbef[4], sC[i+1]); astD(&R.Sbef[4], sS[i+1]); }
      }
    }
  }
  gridbar(cnt, 6);

  // ---------- ph8: q4 L2 hist ----------
  {
    if (tid == 0){ sMode = aldI(&rows[b].q4mode); sB[0] = aldU(&rows[b].cutBin[4]); }
    __syncthreads();
    if (sMode == 0){
      double* hS = (double*)smem;
      unsigned* hC = (unsigned*)(smem + 4096);
      for (int i = tid; i < NB2; i += MT){ hS[i] = 0.0; hC[i] = 0u; }
      __syncthreads();
      unsigned tb = sB[0];
      for (int j = tid; j < QV4; j += MT){
        uint4 kk = K4[j];
        #pragma unroll
        for (int c = 0; c < 4; ++c){
          unsigned K = (c==0)?kk.x:(c==1)?kk.y:(c==2)?kk.z:kk.w;
          if ((K >> 21) == tb){
            unsigned sub = (K >> 12) & (NB2-1);
            unsafeAtomicAdd(&hS[sub], (double)__uint_as_float(K)); atomicAdd(&hC[sub], 1u);
          }
        }
      }
      __syncthreads();
      for (int i = tid; i < NB2; i += MT){
        if (hC[i]){
          unsafeAtomicAdd(&L2S[((size_t)b*5 + 4)*NB2 + i], hS[i]);
          atomicAdd(&L2C[((size_t)b*5 + 4)*NB2 + i], hC[i]);
        }
      }
    }
  }
  gridbar(cnt, 7);

  // ---------- ph9: q4 walk (blocks 0..127) ----------
  if (g < Bn){
    int r = g;
    RowWS& R = rows[r];
    if (tid == 0) sMode = aldI(&R.q4mode);
    __syncthreads();
    if (sMode == 0){
      double* sS = (double*)smem;
      unsigned* sC = (unsigned*)(smem + 4104);
      if (tid == 0){
        sS[512] = 0.0; sC[512] = 0u; mx0 = -1; mnz = NB2;
        snapC = aldU(&R.Cbef[4]); snapS = aldD(&R.Sbef[4]);
        snapCut = aldU(&R.cutBin[4]); sT4d = (double)aldF(&R.t4);
        sMode = aldI(&R.i0);
      }
      unsigned cA = aldU(&L2C[((size_t)r*5+4)*NB2 + tid]);
      unsigned cB = aldU(&L2C[((size_t)r*5+4)*NB2 + tid + 256]);
      sS[tid] = aldD(&L2S[((size_t)r*5+4)*NB2 + tid]);
      sS[tid+256] = aldD(&L2S[((size_t)r*5+4)*NB2 + tid + 256]);
      sC[tid] = cA; sC[tid+256] = cB;
      __syncthreads();
      scan512(sS, sC);
      double baseS = snapS, t4d = sT4d;
      if (cA){ if (baseS + sS[tid] >= t4d) atomicMax(&mx0, tid); atomicMin(&mnz, tid); }
      if (cB){ int t2 = tid+256; if (baseS + sS[t2] >= t4d) atomicMax(&mx0, t2); atomicMin(&mnz, t2); }
      __syncthreads();
      int w = (mx0 >= 0) ? mx0 : ((mnz < NB2) ? mnz : -1);
      if (w < 0){
        if (tid == 0){ astI(&R.q4mode, 2); astI(&R.token, sMode); }
      } else {
        #pragma unroll
        for (int h = 0; h < 2; ++h){
          int i = tid + h*256;
          if (i == w){
            astU(&R.cutPre[4], (snapCut << 9) | (unsigned)i);
            astU(&R.Cbef[4], snapC + sC[i+1]); astD(&R.Sbef[4], snapS + sS[i+1]);
          }
        }
      }
    }
  }
  gridbar(cnt, 8);

  // ---------- ph10: write logprobs (in-place over Kc) + collect q4 ----------
  {
    if (tid == 0){
      sV2 = aldU(&rows[b].v2); sI2 = aldI(&rows[b].i2); sS2f = aldF(&rows[b].S2f);
      sMode = aldI(&rows[b].q4mode); sT4p = aldU(&rows[b].cutPre[4]);
    }
    __syncthreads();
    unsigned v2 = sV2; int i2 = sI2; float S2f = sS2f;
    bool doColl = (sMode == 0);
    unsigned t4p = sT4p;
    int ibase = qq*QLEN;
    float4* O4 = (float4*)K4;
    for (int j = tid; j < QV4; j += MT){
      uint4 kk = K4[j];
      float4 o;
      #pragma unroll
      for (int c = 0; c < 4; ++c){
        unsigned K = (c==0)?kk.x:(c==1)?kk.y:(c==2)?kk.z:kk.w;
        int i = ibase + j*4 + c;
        if (doColl && (K >> 12) == t4p){
          unsigned pos = atomicAdd(&lcnt[b*8+4], 1u);
          if (pos < CAP) astL(&lists[((size_t)b*5+4)*CAP + pos], (((unsigned long long)(~K)) << 32) | (unsigned)i);
        }
        float p = __uint_as_float(K);
        float val = (K > v2 || (K == v2 && i <= i2)) ? fmaxf(logf(p / S2f), FMINV) : FOUT;
        if (c==0) o.x = val; else if (c==1) o.y = val; else if (c==2) o.z = val; else o.w = val;
      }
      O4[j] = o;
    }
  }
  gridbar(cnt, 9);

  // ---------- ph11: pick token (blocks 0..127) ----------
  if (g < Bn){
    int r = g;
    RowWS& R = rows[r];
    unsigned long long* Ls = (unsigned long long*)smem;
    if (tid == 0) sMode = aldI(&R.q4mode);
    __syncthreads();
    int n = (int)aldU(&lcnt[r*8+4]); if (n > CAP) n = CAP;
    if (sMode != 2)
      for (int j = tid; j < n; j += MT) Ls[j] = aldL(&lists[((size_t)r*5+4)*CAP + j]);
    __syncthreads();
    if (tid == 0){
      int token; unsigned pB;
      unsigned v0 = aldU(&R.v0); int i0 = aldI(&R.i0);
      if (sMode == 2){ token = aldI(&R.token); pB = v0; }
      else {
        for (int i2 = 1; i2 < n; ++i2){
          unsigned long long key = Ls[i2]; int j = i2-1;
          while (j >= 0 && Ls[j] > key){ Ls[j+1] = Ls[j]; --j; }
          Ls[j+1] = key;
        }
        double S = aldD(&R.Sbef[4]), t4d = (double)aldF(&R.t4);
        token = -1; pB = v0;
        for (int j = 0; j < n; ++j){
          unsigned K = ~(unsigned)(Ls[j] >> 32);
          int idx = (int)(unsigned)(Ls[j] & 0xFFFFFFFFu);
          bool kept = (K > v0) || (K == v0 && idx <= i0);
          if (!kept){ token = i0; pB = v0; break; }
          S += (double)__uint_as_float(K);
          if (S >= t4d){ token = idx; pB = K; break; }
        }
        if (token < 0){ token = i0; pB = v0; }
      }
      unsigned v2 = aldU(&R.v2); int i2 = aldI(&R.i2);
      float S2f = aldF(&R.S2f);
      bool kept2 = (pB > v2) || (pB == v2 && token <= i2);
      float pt = __uint_as_float(pB);
      float lp = kept2 ? fmaxf(logf(pt / S2f), FMINV) : FOUT;
      outTok[r] = (float)token;
      outNtlp[r] = lp;
    }
  }
}

extern "C" void kernel_launch(void* const* d_in, const int* in_sizes, int n_in,
                              void* d_out, int out_size, void* d_ws, size_t ws_size,
                              hipStream_t stream)
{
  const float* logits  = (const float*)d_in[0];
  const float* temps   = (const float*)d_in[1];
  const int*   top_ks  = (const int*)d_in[2];
  const float* top_ps  = (const float*)d_in[3];
  const float* top_ps2 = (const float*)d_in[4];
  const float* min_ps  = (const float*)d_in[5];
  const float* uarr    = (const float*)d_in[6];

  float* outTok  = (float*)d_out;
  float* outLp   = outTok + Bn;
  float* outNtlp = outLp + (size_t)Bn * Vn;

  hipMemsetAsync(d_ws, 0, ZERO_BYTES, stream);
  mega<<<NBLK, MT, 0, stream>>>(logits, temps, top_ks, top_ps, top_ps2, min_ps,
                                uarr, (char*)d_ws, outTok, outLp, outNtlp);
}

// Round 7
// 400.170 us; speedup vs baseline: 1.1657x; 1.1657x over previous
//
#include <hip/hip_runtime.h>

#define Bn 128
#define Vn 128000
#define SLN 16000          // slice length (Vn/8)
#define SL4 4000           // SLN/4
#define NB 512             // bins at both levels
#define CAPQ 512           // per-query candidate list cap
#define SKCAP 2560         // kept-superset cap (<=2046 above prefix + in-prefix)
#define FMINV -3.4028234663852886e38f   // internal clamp (ref finfo.min)
#define FOUT  -3.3895313892515355e38f   // 0xFF7F0000 max-finite bf16 for masked outputs

// ---- ws arena (bytes), total ~8.69 MB ----
#define OFF_CTRA 0u
#define OFF_CTRB 512u
#define OFF_CTRC 1024u
#define OFF_CTRD 1536u
#define OFF_ROWS 4096u      // 128 * 128
#define OFF_SLM  20480u     // f32[1024]
#define OFF_SLZ  24576u     // f64[1024]
#define OFF_L1S  32768u     // f64[128][512]
#define OFF_L1C  557056u    // u32[128][512]
#define OFF_L2S  819200u    // f64[128][4][512]
#define OFF_L2C  2916352u   // u32[128][4][512]
#define OFF_LCNT 3964928u   // u32[128][4]
#define OFF_SKC  3966976u   // u32[128]
#define ZERO_BYTES 3967488u
#define OFF_QL   3967488u   // u64[128][4][512]
#define OFF_SK   6064640u   // u64[128][2560]

struct RowWS {
  float A, Zf, S2f; unsigned thrBits;
  unsigned v2; int i2; unsigned supP, pad0;
  unsigned cutBin[4], cutPre[4], Cbef[4];
  double Sbef[4];
  double pad1[2];
};

__device__ __forceinline__ unsigned aldU(const unsigned* p){ return __hip_atomic_load((unsigned*)p, __ATOMIC_RELAXED, __HIP_MEMORY_SCOPE_AGENT); }
__device__ __forceinline__ float aldF(const float* p){ return __hip_atomic_load((float*)p, __ATOMIC_RELAXED, __HIP_MEMORY_SCOPE_AGENT); }
__device__ __forceinline__ double aldD(const double* p){ return __hip_atomic_load((double*)p, __ATOMIC_RELAXED, __HIP_MEMORY_SCOPE_AGENT); }
__device__ __forceinline__ unsigned long long aldL(const unsigned long long* p){ return __hip_atomic_load((unsigned long long*)p, __ATOMIC_RELAXED, __HIP_MEMORY_SCOPE_AGENT); }
__device__ __forceinline__ void astF(float* p, float v){ __hip_atomic_store(p, v, __ATOMIC_RELAXED, __HIP_MEMORY_SCOPE_AGENT); }
__device__ __forceinline__ void astD(double* p, double v){ __hip_atomic_store(p, v, __ATOMIC_RELAXED, __HIP_MEMORY_SCOPE_AGENT); }
__device__ __forceinline__ void astL(unsigned long long* p, unsigned long long v){ __hip_atomic_store(p, v, __ATOMIC_RELAXED, __HIP_MEMORY_SCOPE_AGENT); }
// release our prior writes, acquire others' once we're the 8th arriver
__device__ __forceinline__ unsigned arrive(unsigned* c){ return __hip_atomic_fetch_add(c, 1u, __ATOMIC_ACQ_REL, __HIP_MEMORY_SCOPE_AGENT); }

// suffix scan over 512 bins with 256 threads (each owns t and t+256); [512] must be 0
__device__ __forceinline__ void scan512(double* sS, unsigned* sC){
  int t = threadIdx.x;
  for (int off = 1; off < 512; off <<= 1){
    double a1 = sS[t], b1 = (t+off < 512) ? sS[t+off] : 0.0;
    double a2 = sS[t+256], b2 = (t+256+off < 512) ? sS[t+256+off] : 0.0;
    unsigned c1 = sC[t], d1 = (t+off < 512) ? sC[t+off] : 0u;
    unsigned c2 = sC[t+256], d2 = (t+256+off < 512) ? sC[t+256+off] : 0u;
    __syncthreads();
    sS[t] = a1 + b1; sS[t+256] = a2 + b2;
    sC[t] = c1 + d1; sC[t+256] = c2 + d2;
    __syncthreads();
  }
}

// ---- A: slice max + exp-sum; last block combines -> A, Zf, thrBits ----
__global__ __launch_bounds__(256) void kA(const float* __restrict__ logits,
    const float* __restrict__ temps, const float* __restrict__ min_ps, char* ws){
  __shared__ float sF[4]; __shared__ double sD[4];
  __shared__ float sMax; __shared__ int sLast;
  unsigned* ctr = (unsigned*)(ws + OFF_CTRA);
  float* sliceM = (float*)(ws + OFF_SLM);
  double* sliceZ = (double*)(ws + OFF_SLZ);
  RowWS* rows = (RowWS*)(ws + OFF_ROWS);
  int g = blockIdx.x, b = g >> 3, tid = threadIdx.x;
  const float4* l4 = (const float4*)(logits + (size_t)b*Vn + (size_t)(g & 7)*SLN);
  float T = temps[b];
  float m = -3.4e38f;
  for (int j = tid; j < SL4; j += 256){
    float4 v = l4[j];
    m = fmaxf(m, fmaxf(fmaxf(v.x, v.y), fmaxf(v.z, v.w)));
  }
  #pragma unroll
  for (int o = 32; o; o >>= 1) m = fmaxf(m, __shfl_down(m, o));
  if ((tid & 63) == 0) sF[tid >> 6] = m;
  __syncthreads();
  if (tid == 0){ float mm = sF[0]; for (int w = 1; w < 4; ++w) mm = fmaxf(mm, sF[w]); sMax = mm; }
  __syncthreads();
  float a = sMax / T;
  double z = 0.0;
  for (int j = tid; j < SL4; j += 256){
    float4 v = l4[j];
    z += (double)expf(v.x/T - a) + (double)expf(v.y/T - a)
       + (double)expf(v.z/T - a) + (double)expf(v.w/T - a);
  }
  #pragma unroll
  for (int o = 32; o; o >>= 1) z += __shfl_down(z, o);
  if ((tid & 63) == 0) sD[tid >> 6] = z;
  __syncthreads();
  if (tid == 0){
    double zz = 0.0; for (int w = 0; w < 4; ++w) zz += sD[w];
    astF(&sliceM[g], sMax); astD(&sliceZ[g], zz);
    sLast = (arrive(&ctr[b]) == 7u);
  }
  __syncthreads();
  if (sLast && tid == 0){
    float M = aldF(&sliceM[b*8]);
    for (int s = 1; s < 8; ++s) M = fmaxf(M, aldF(&sliceM[b*8+s]));
    float A = M / T;
    double Z = 0.0;
    for (int s = 0; s < 8; ++s)
      Z += aldD(&sliceZ[b*8+s]) * exp((double)(aldF(&sliceM[b*8+s]) / T) - (double)A);
    float Zf = (float)Z;
    rows[b].A = A; rows[b].Zf = Zf;
    rows[b].thrBits = __float_as_uint((1.0f / Zf) * min_ps[b]);  // p_max = 1/Zf exactly
  }
}

// ---- B: K once -> Kc + L1 hist; last block does L1 walk ----
__global__ __launch_bounds__(256) void kB(const float* __restrict__ logits,
    const float* __restrict__ temps, char* ws, unsigned* __restrict__ Kc,
    const int* __restrict__ top_ks, const float* __restrict__ top_ps,
    const float* __restrict__ top_ps2){
  __shared__ double   hS[4*NB];
  __shared__ unsigned hC[4*NB];
  __shared__ int sLast, mx0, mx1, mx2, mnz;
  unsigned* ctr = (unsigned*)(ws + OFF_CTRB);
  RowWS* rows = (RowWS*)(ws + OFF_ROWS);
  double* L1S = (double*)(ws + OFF_L1S);
  unsigned* L1C = (unsigned*)(ws + OFF_L1C);
  int g = blockIdx.x, b = g >> 3, tid = threadIdx.x;
  size_t base = (size_t)b*Vn + (size_t)(g & 7)*SLN;
  const float4* l4 = (const float4*)(logits + base);
  uint4* K4 = (uint4*)(Kc + base);
  float T = temps[b], A = rows[b].A, Zf = rows[b].Zf;
  for (int i = tid; i < 4*NB; i += 256){ hS[i] = 0.0; hC[i] = 0u; }
  __syncthreads();
  int cp = (tid >> 6) & 3;
  for (int j = tid; j < SL4; j += 256){
    float4 v = l4[j];
    uint4 kk;
    float p0 = expf(v.x/T - A) / Zf; kk.x = __float_as_uint(p0);
    float p1 = expf(v.y/T - A) / Zf; kk.y = __float_as_uint(p1);
    float p2 = expf(v.z/T - A) / Zf; kk.z = __float_as_uint(p2);
    float p3 = expf(v.w/T - A) / Zf; kk.w = __float_as_uint(p3);
    unsigned b0 = min(kk.x >> 21, NB-1u), b1 = min(kk.y >> 21, NB-1u);
    unsigned b2 = min(kk.z >> 21, NB-1u), b3 = min(kk.w >> 21, NB-1u);
    unsafeAtomicAdd(&hS[cp*NB + b0], (double)p0); atomicAdd(&hC[cp*NB + b0], 1u);
    unsafeAtomicAdd(&hS[cp*NB + b1], (double)p1); atomicAdd(&hC[cp*NB + b1], 1u);
    unsafeAtomicAdd(&hS[cp*NB + b2], (double)p2); atomicAdd(&hC[cp*NB + b2], 1u);
    unsafeAtomicAdd(&hS[cp*NB + b3], (double)p3); atomicAdd(&hC[cp*NB + b3], 1u);
    K4[j] = kk;
  }
  __syncthreads();
  for (int bin = tid; bin < NB; bin += 256){
    unsigned c = hC[bin] + hC[NB+bin] + hC[2*NB+bin] + hC[3*NB+bin];
    if (c){
      double s = hS[bin] + hS[NB+bin] + hS[2*NB+bin] + hS[3*NB+bin];
      unsafeAtomicAdd(&L1S[(size_t)b*NB + bin], s);
      atomicAdd(&L1C[(size_t)b*NB + bin], c);
    }
  }
  if (tid == 0) sLast = (arrive(&ctr[b]) == 7u);
  __syncthreads();
  if (!sLast) return;
  // ---- L1 walk (reuse LDS) ----
  double* sS = hS;                       // 513 f64
  unsigned* sC = hC;                     // 513 u32
  if (tid == 0){ sS[512] = 0.0; sC[512] = 0u; mx0 = -1; mx1 = -1; mx2 = -1; mnz = NB; }
  unsigned cA = aldU(&L1C[(size_t)b*NB + tid]);
  unsigned cB2 = aldU(&L1C[(size_t)b*NB + tid + 256]);
  double vA = aldD(&L1S[(size_t)b*NB + tid]);
  double vB = aldD(&L1S[(size_t)b*NB + tid + 256]);
  __syncthreads();
  sS[tid] = vA; sS[tid+256] = vB; sC[tid] = cA; sC[tid+256] = cB2;
  __syncthreads();
  scan512(sS, sC);
  RowWS& R = rows[b];
  unsigned thrBits = R.thrBits;
  int thrBin = (int)(thrBits >> 21); if (thrBin > NB-1) thrBin = NB-1;
  unsigned k = (unsigned)top_ks[b];
  double tauP = (double)top_ps[b], tauP2 = (double)top_ps2[b];
  if (cA){
    if (sC[tid] >= k)    atomicMax(&mx0, tid);
    if (sS[tid] > tauP ) atomicMax(&mx1, tid);
    if (sS[tid] > tauP2) atomicMax(&mx2, tid);
    atomicMin(&mnz, tid);
  }
  if (cB2){
    int t2 = tid + 256;
    if (sC[t2] >= k)    atomicMax(&mx0, t2);
    if (sS[t2] > tauP ) atomicMax(&mx1, t2);
    if (sS[t2] > tauP2) atomicMax(&mx2, t2);
    atomicMin(&mnz, t2);
  }
  __syncthreads();
  int w0 = mx0, w1 = (mx1 >= 0) ? mx1 : mnz, w2 = (mx2 >= 0) ? mx2 : mnz;
  #pragma unroll
  for (int h = 0; h < 2; ++h){
    int i = tid + h*256;
    if (i == thrBin){ R.cutBin[3] = (unsigned)i; R.Cbef[3] = sC[i+1]; R.Sbef[3] = sS[i+1]; }
    if (i == w0){ R.cutBin[0] = (unsigned)i; R.Cbef[0] = sC[i+1]; R.Sbef[0] = sS[i+1]; }
    if (i == w1){ R.cutBin[1] = (unsigned)i; R.Cbef[1] = sC[i+1]; R.Sbef[1] = sS[i+1]; }
    if (i == w2){ R.cutBin[2] = (unsigned)i; R.Cbef[2] = sC[i+1]; R.Sbef[2] = sS[i+1]; }
  }
}

// ---- C: L2 hists q0..q3; last block does all 4 L2 walks + supP ----
__global__ __launch_bounds__(256) void kC(const float* __restrict__ temps, char* ws,
    const unsigned* __restrict__ Kc, const int* __restrict__ top_ks,
    const float* __restrict__ top_ps, const float* __restrict__ top_ps2){
  __shared__ double   hS[4*NB];
  __shared__ unsigned hC[4*NB];
  __shared__ unsigned sTB[4], sCutPre[4];
  __shared__ int sLast, mx0, mnz;
  __shared__ unsigned snapC, snapCut;
  __shared__ double snapS;
  unsigned* ctr = (unsigned*)(ws + OFF_CTRC);
  RowWS* rows = (RowWS*)(ws + OFF_ROWS);
  double* L2S = (double*)(ws + OFF_L2S);
  unsigned* L2C = (unsigned*)(ws + OFF_L2C);
  int g = blockIdx.x, b = g >> 3, tid = threadIdx.x;
  const uint4* K4 = (const uint4*)(Kc + (size_t)b*Vn + (size_t)(g & 7)*SLN);
  if (tid == 0){
    sTB[0] = rows[b].cutBin[0]; sTB[1] = rows[b].cutBin[1];
    sTB[2] = rows[b].cutBin[2]; sTB[3] = rows[b].cutBin[3];
  }
  for (int i = tid; i < 4*NB; i += 256){ hS[i] = 0.0; hC[i] = 0u; }
  __syncthreads();
  unsigned tb0 = sTB[0], tb1 = sTB[1], tb2 = sTB[2], tb3 = sTB[3];
  for (int j = tid; j < SL4; j += 256){
    uint4 kk = K4[j];
    #pragma unroll
    for (int c = 0; c < 4; ++c){
      unsigned K = (c==0)?kk.x:(c==1)?kk.y:(c==2)?kk.z:kk.w;
      unsigned bin = K >> 21, sub = (K >> 12) & (NB-1);
      double p = (double)__uint_as_float(K);
      if (bin == tb0){ unsafeAtomicAdd(&hS[0*NB+sub], p); atomicAdd(&hC[0*NB+sub], 1u); }
      if (bin == tb1){ unsafeAtomicAdd(&hS[1*NB+sub], p); atomicAdd(&hC[1*NB+sub], 1u); }
      if (bin == tb2){ unsafeAtomicAdd(&hS[2*NB+sub], p); atomicAdd(&hC[2*NB+sub], 1u); }
      if (bin == tb3){ unsafeAtomicAdd(&hS[3*NB+sub], p); atomicAdd(&hC[3*NB+sub], 1u); }
    }
  }
  __syncthreads();
  for (int i = tid; i < 4*NB; i += 256){
    if (hC[i]){
      unsafeAtomicAdd(&L2S[((size_t)b*4)*NB + i], hS[i]);
      atomicAdd(&L2C[((size_t)b*4)*NB + i], hC[i]);
    }
  }
  if (tid == 0) sLast = (arrive(&ctr[b]) == 7u);
  __syncthreads();
  if (!sLast) return;
  RowWS& R = rows[b];
  double* sS = hS; unsigned* sC = hC;
  for (int q = 0; q < 4; ++q){
    __syncthreads();
    if (tid == 0){
      sS[512] = 0.0; sC[512] = 0u; mx0 = -1; mnz = NB;
      snapC = R.Cbef[q]; snapS = R.Sbef[q]; snapCut = R.cutBin[q];
    }
    unsigned cA = aldU(&L2C[((size_t)b*4+q)*NB + tid]);
    unsigned cB2 = aldU(&L2C[((size_t)b*4+q)*NB + tid + 256]);
    double vA = aldD(&L2S[((size_t)b*4+q)*NB + tid]);
    double vB = aldD(&L2S[((size_t)b*4+q)*NB + tid + 256]);
    __syncthreads();
    sS[tid] = vA; sS[tid+256] = vB; sC[tid] = cA; sC[tid+256] = cB2;
    __syncthreads();
    scan512(sS, sC);
    unsigned baseC = snapC, cutBin = snapCut; double baseS = snapS;
    if (q == 3){
      int thrSub = (int)((R.thrBits >> 12) & (NB-1));
      #pragma unroll
      for (int h = 0; h < 2; ++h){
        int i = tid + h*256;
        if (i == thrSub){
          unsigned cp = (cutBin << 9) | (unsigned)i;
          R.cutPre[3] = cp; sCutPre[3] = cp;
          R.Cbef[3] = baseC + sC[i+1]; R.Sbef[3] = baseS + sS[i+1];
        }
      }
    } else {
      unsigned k = (unsigned)top_ks[b];
      double tau = (q == 1) ? (double)top_ps[b] : (double)top_ps2[b];
      if (cA){
        if (q == 0){ if (baseC + sC[tid] >= k) atomicMax(&mx0, tid); }
        else       { if (baseS + sS[tid] > tau) atomicMax(&mx0, tid); }
        atomicMin(&mnz, tid);
      }
      if (cB2){
        int t2 = tid + 256;
        if (q == 0){ if (baseC + sC[t2] >= k) atomicMax(&mx0, t2); }
        else       { if (baseS + sS[t2] > tau) atomicMax(&mx0, t2); }
        atomicMin(&mnz, t2);
      }
      __syncthreads();
      int w = (mx0 >= 0) ? mx0 : mnz;
      #pragma unroll
      for (int h = 0; h < 2; ++h){
        int i = tid + h*256;
        if (i == w){
          unsigned cp = (cutBin << 9) | (unsigned)i;
          R.cutPre[q] = cp; sCutPre[q] = cp;
          R.Cbef[q] = baseC + sC[i+1]; R.Sbef[q] = baseS + sS[i+1];
        }
      }
    }
  }
  __syncthreads();
  if (tid == 0){
    unsigned P = sCutPre[0];
    if (sCutPre[1] > P) P = sCutPre[1];
    if (sCutPre[3] > P) P = sCutPre[3];
    R.supP = P;
  }
}

// ---- D: collect q-lists + kept-superset; last block: resolve + sort + sample ----
__global__ __launch_bounds__(256) void kD(char* ws, const unsigned* __restrict__ Kc,
    const int* __restrict__ top_ks, const float* __restrict__ top_ps,
    const float* __restrict__ top_ps2, const float* __restrict__ uarr,
    float* __restrict__ outTok, float* __restrict__ outNtlp){
  __shared__ unsigned long long sLsQ[4*CAPQ];   // 16 KB
  __shared__ unsigned long long sSKL[4096];     // 32 KB
  __shared__ double sCh[256];
  __shared__ unsigned sT[4], sP;
  __shared__ int sLast, sPos, sP2;
  __shared__ unsigned sV0, sV2;
  __shared__ int sI0, sI2;
  __shared__ float sS2f;
  __shared__ double sT4d;
  unsigned* ctr = (unsigned*)(ws + OFF_CTRD);
  RowWS* rows = (RowWS*)(ws + OFF_ROWS);
  unsigned* lcnt = (unsigned*)(ws + OFF_LCNT);
  unsigned* skc = (unsigned*)(ws + OFF_SKC);
  unsigned long long* ql = (unsigned long long*)(ws + OFF_QL);
  unsigned long long* SK = (unsigned long long*)(ws + OFF_SK);
  int g = blockIdx.x, b = g >> 3, sl = g & 7, tid = threadIdx.x;
  if (tid == 0){
    sT[0] = rows[b].cutPre[0]; sT[1] = rows[b].cutPre[1];
    sT[2] = rows[b].cutPre[2]; sT[3] = rows[b].cutPre[3];
    sP = rows[b].supP;
  }
  __syncthreads();
  unsigned t0 = sT[0], t1 = sT[1], t2 = sT[2], t3 = sT[3], P = sP;
  int ibase = sl*SLN;
  const uint4* K4 = (const uint4*)(Kc + (size_t)b*Vn + ibase);
  for (int j = tid; j < SL4; j += 256){
    uint4 kk = K4[j];
    #pragma unroll
    for (int c = 0; c < 4; ++c){
      unsigned K = (c==0)?kk.x:(c==1)?kk.y:(c==2)?kk.z:kk.w;
      unsigned pre = K >> 12;
      if (pre < P && pre != t0 && pre != t1 && pre != t2 && pre != t3) continue;
      int i = ibase + j*4 + c;
      unsigned long long e = (((unsigned long long)(~K)) << 32) | (unsigned)i;
      if (pre == t0){ unsigned pos = atomicAdd(&lcnt[b*4+0], 1u); if (pos < CAPQ) astL(&ql[((size_t)b*4+0)*CAPQ+pos], e); }
      if (pre == t1){ unsigned pos = atomicAdd(&lcnt[b*4+1], 1u); if (pos < CAPQ) astL(&ql[((size_t)b*4+1)*CAPQ+pos], e); }
      if (pre == t2){ unsigned pos = atomicAdd(&lcnt[b*4+2], 1u); if (pos < CAPQ) astL(&ql[((size_t)b*4+2)*CAPQ+pos], e); }
      if (pre == t3){ unsigned pos = atomicAdd(&lcnt[b*4+3], 1u); if (pos < CAPQ) astL(&ql[((size_t)b*4+3)*CAPQ+pos], e); }
      if (pre >= P){ unsigned pos = atomicAdd(&skc[b], 1u); if (pos < SKCAP) astL(&SK[(size_t)b*SKCAP+pos], e); }
    }
  }
  if (tid == 0) sLast = (arrive(&ctr[b]) == 7u);
  __syncthreads();
  if (!sLast) return;
  RowWS& R = rows[b];
  int nq[4];
  for (int q = 0; q < 4; ++q){
    int n = (int)aldU(&lcnt[b*4+q]); if (n > CAPQ) n = CAPQ; nq[q] = n;
    for (int j = tid; j < n; j += 256) sLsQ[q*CAPQ+j] = aldL(&ql[((size_t)b*4+q)*CAPQ + j]);
  }
  int nsk = (int)aldU(&skc[b]); if (nsk > SKCAP) nsk = SKCAP;
  for (int j = tid; j < 4096; j += 256) sSKL[j] = 0xFFFFFFFFFFFFFFFFull;
  __syncthreads();
  for (int j = tid; j < nsk; j += 256) sSKL[j] = aldL(&SK[(size_t)b*SKCAP + j]);
  if (tid == 0){
    int p2 = 2; while (p2 < nsk) p2 <<= 1;
    sP2 = p2; sPos = 0x7FFFFFFF;
  }
  __syncthreads();
  // bitonic sort ascending (e = (~K)<<32|idx  ->  p desc, idx asc)
  int P2 = sP2;
  for (unsigned kk2 = 2; kk2 <= (unsigned)P2; kk2 <<= 1){
    for (unsigned jj = kk2 >> 1; jj > 0; jj >>= 1){
      for (int i = tid; i < P2; i += 256){
        int ixj = i ^ (int)jj;
        if (ixj > i){
          unsigned long long a = sSKL[i], bb = sSKL[ixj];
          bool up = ((i & kk2) == 0);
          if ((a > bb) == up){ sSKL[i] = bb; sSKL[ixj] = a; }
        }
      }
      __syncthreads();
    }
  }
  // serial q-resolution (small lists)
  if (tid == 0){
    int k = top_ks[b];
    double tauP = (double)top_ps[b], tauP2 = (double)top_ps2[b];
    unsigned thrB = R.thrBits;
    unsigned vS[4]; int iS[4]; double sk[4];
    for (int q = 0; q < 4; ++q){
      int n = nq[q];
      unsigned long long* L = &sLsQ[q*CAPQ];
      for (int i2 = 1; i2 < n; ++i2){
        unsigned long long key = L[i2]; int j = i2-1;
        while (j >= 0 && L[j] > key){ L[j+1] = L[j]; --j; }
        L[j+1] = key;
      }
      double S = R.Sbef[q];
      if (q == 0){
        if (n > 0){
          int mm = k - (int)R.Cbef[0]; if (mm < 1) mm = 1; if (mm > n) mm = n;
          for (int j = 0; j < mm; ++j){ unsigned K = ~(unsigned)(L[j] >> 32); S += (double)__uint_as_float(K); }
          unsigned long long e = L[mm-1];
          vS[0] = ~(unsigned)(e >> 32); iS[0] = (int)(unsigned)(e & 0xFFFFFFFFu); sk[0] = S;
        } else { vS[0] = 0u; iS[0] = 0x7FFFFFFF; sk[0] = S; }
      } else if (q < 3){
        double tau = (q == 1) ? tauP : tauP2;
        int last = -1;
        for (int j = 0; j < n; ++j){
          if (S > tau) break;
          unsigned K = ~(unsigned)(L[j] >> 32);
          S += (double)__uint_as_float(K); last = j;
        }
        if (n > 0){
          int pick = (last < 0) ? 0 : last;
          unsigned long long e = L[pick];
          vS[q] = ~(unsigned)(e >> 32); iS[q] = (int)(unsigned)(e & 0xFFFFFFFFu); sk[q] = S;
        } else { vS[q] = 0u; iS[q] = 0x7FFFFFFF; sk[q] = S; }
      } else {
        for (int j = 0; j < n; ++j){
          unsigned K = ~(unsigned)(L[j] >> 32);
          if (K < thrB) break;
          S += (double)__uint_as_float(K);
        }
        vS[3] = thrB; iS[3] = 0x7FFFFFFF; sk[3] = S;
      }
    }
    unsigned v0 = vS[0]; int i0 = iS[0]; double tot = sk[0];
    if (vS[1] > v0 || (vS[1] == v0 && iS[1] < i0)){ v0 = vS[1]; i0 = iS[1]; tot = sk[1]; }
    if (vS[3] > v0 || (vS[3] == v0 && iS[3] < i0)){ v0 = vS[3]; i0 = iS[3]; tot = sk[3]; }
    sV0 = v0; sI0 = i0;
    sV2 = vS[2]; sI2 = iS[2]; sS2f = (float)sk[2];
    R.v2 = vS[2]; R.i2 = iS[2]; R.S2f = (float)sk[2];
    sT4d = (double)(uarr[b] * (float)tot);
  }
  __syncthreads();
  // chunked f64 CDF over sorted kept elements; find first run >= t4
  {
    unsigned v0 = sV0; int i0 = sI0; double t4d = sT4d;
    int c0 = tid * 16;
    double loc = 0.0;
    #pragma unroll
    for (int ii = 0; ii < 16; ++ii){
      unsigned long long e = sSKL[c0+ii];
      unsigned K = ~(unsigned)(e >> 32); int idx = (int)(unsigned)(e & 0xFFFFFFFFu);
      bool kept = (K > v0) || (K == v0 && idx <= i0);
      if (kept) loc += (double)__uint_as_float(K);
    }
    sCh[tid] = loc;
    __syncthreads();
    for (int off = 1; off < 256; off <<= 1){
      double v = sCh[tid] + ((tid >= off) ? sCh[tid-off] : 0.0);
      __syncthreads(); sCh[tid] = v; __syncthreads();
    }
    double run = sCh[tid] - loc;   // exclusive base
    for (int ii = 0; ii < 16; ++ii){
      unsigned long long e = sSKL[c0+ii];
      unsigned K = ~(unsigned)(e >> 32); int idx = (int)(unsigned)(e & 0xFFFFFFFFu);
      bool kept = (K > v0) || (K == v0 && idx <= i0);
      if (kept) run += (double)__uint_as_float(K);
      if (run >= t4d){ atomicMin(&sPos, c0+ii); break; }
    }
  }
  __syncthreads();
  if (tid == 0){
    int token; unsigned pB;
    if (sPos == 0x7FFFFFFF){ token = sI0; pB = sV0; }
    else {
      unsigned long long e = sSKL[sPos];
      pB = ~(unsigned)(e >> 32); token = (int)(unsigned)(e & 0xFFFFFFFFu);
    }
    unsigned v2 = sV2; int i2 = sI2;
    bool kept2 = (pB > v2) || (pB == v2 && token <= i2);
    float pt = __uint_as_float(pB);
    float lp = kept2 ? fmaxf(logf(pt / sS2f), FMINV) : FOUT;
    outTok[b] = (float)token;
    outNtlp[b] = lp;
  }
}

// ---- E: logprobs write (in place over Kc) ----
__global__ __launch_bounds__(256) void kE(const char* __restrict__ ws, float* __restrict__ outLp){
  const RowWS* rows = (const RowWS*)(ws + OFF_ROWS);
  int g = blockIdx.x, b = g >> 3, sl = g & 7, tid = threadIdx.x;
  unsigned v2 = rows[b].v2; int i2 = rows[b].i2; float S2f = rows[b].S2f;
  int ibase = sl*SLN;
  float4* O4 = (float4*)(outLp + (size_t)b*Vn + ibase);
  const uint4* K4 = (const uint4*)O4;
  for (int j = tid; j < SL4; j += 256){
    uint4 kk = K4[j];
    float4 o;
    #pragma unroll
    for (int c = 0; c < 4; ++c){
      unsigned K = (c==0)?kk.x:(c==1)?kk.y:(c==2)?kk.z:kk.w;
      int i = ibase + j*4 + c;
      float p = __uint_as_float(K);
      float val = (K > v2 || (K == v2 && i <= i2)) ? fmaxf(logf(p / S2f), FMINV) : FOUT;
      if (c==0) o.x = val; else if (c==1) o.y = val; else if (c==2) o.z = val; else o.w = val;
    }
    O4[j] = o;
  }
}

extern "C" void kernel_launch(void* const* d_in, const int* in_sizes, int n_in,
                              void* d_out, int out_size, void* d_ws, size_t ws_size,
                              hipStream_t stream)
{
  const float* logits  = (const float*)d_in[0];
  const float* temps   = (const float*)d_in[1];
  const int*   top_ks  = (const int*)d_in[2];
  const float* top_ps  = (const float*)d_in[3];
  const float* top_ps2 = (const float*)d_in[4];
  const float* min_ps  = (const float*)d_in[5];
  const float* uarr    = (const float*)d_in[6];

  float* outTok  = (float*)d_out;
  float* outLp   = outTok + Bn;
  float* outNtlp = outLp + (size_t)Bn * Vn;
  unsigned* Kc   = (unsigned*)outLp;       // K-cache lives in output buffer

  char* ws = (char*)d_ws;
  hipMemsetAsync(ws, 0, ZERO_BYTES, stream);
  kA<<<1024, 256, 0, stream>>>(logits, temps, min_ps, ws);
  kB<<<1024, 256, 0, stream>>>(logits, temps, ws, Kc, top_ks, top_ps, top_ps2);
  kC<<<1024, 256, 0, stream>>>(temps, ws, Kc, top_ks, top_ps, top_ps2);
  kD<<<1024, 256, 0, stream>>>(ws, Kc, top_ks, top_ps, top_ps2, uarr, outTok, outNtlp);
  kE<<<1024, 256, 0, stream>>>(ws, outLp);
}

// Round 8
// 346.544 us; speedup vs baseline: 1.3461x; 1.1547x over previous
//
#include <hip/hip_runtime.h>

#define Bn 128
#define Vn 128000
#define SLICES 16
#define SLN 8000           // Vn/16
#define SL4 2000           // SLN/4
#define NB 512
#define CAPQ 512
#define SKCAP 2560
#define FMINV -3.4028234663852886e38f   // internal clamp (ref finfo.min)
#define FOUT  -3.3895313892515355e38f   // 0xFF7F0000 max-finite bf16 for masked outputs

// ---- ws arena (bytes), total ~8.70 MB ----
#define OFF_ROWS 0u         // 128 * 160
#define OFF_SLM  24576u     // f32[2048]
#define OFF_SLZ  32768u     // f64[2048]
#define ZSTART   49152u
#define OFF_L1S  49152u     // f64[128][512]
#define OFF_L1C  573440u    // u32[128][512]
#define OFF_L2S  835584u    // f64[128][4][512]
#define OFF_L2C  2932736u   // u32[128][4][512]
#define OFF_LCNT 3981312u   // u32[128][4]
#define OFF_SKC  3983360u   // u32[128]
#define ZBYTES   3934720u   // [ZSTART, 3983872)
#define OFF_QL   3983872u   // u64[128][4][512]
#define OFF_SK   6081024u   // u64[128][2560]

struct RowWS {
  float Zf, S2f; unsigned v2; int i2;
  unsigned supP;
  unsigned cutBin[4], cutPre[4], CbefL1[4], CbefL2[4];
  double SbefL1[4], SbefL2[4];
  unsigned pad[3];
};

// suffix scan over 512 bins with 256 threads (each owns t and t+256)
__device__ __forceinline__ void scan512(double* sS, unsigned* sC){
  int t = threadIdx.x;
  for (int off = 1; off < 512; off <<= 1){
    double a1 = sS[t], b1 = (t+off < 512) ? sS[t+off] : 0.0;
    double a2 = sS[t+256], b2 = (t+256+off < 512) ? sS[t+256+off] : 0.0;
    unsigned c1 = sC[t], d1 = (t+off < 512) ? sC[t+off] : 0u;
    unsigned c2 = sC[t+256], d2 = (t+256+off < 512) ? sC[t+256+off] : 0u;
    __syncthreads();
    sS[t] = a1 + b1; sS[t+256] = a2 + b2;
    sC[t] = c1 + d1; sC[t+256] = c2 + d2;
    __syncthreads();
  }
}

// ---- A: per-slice max + exp-sum ----
__global__ __launch_bounds__(256) void kA(const float* __restrict__ logits,
    const float* __restrict__ temps, char* ws){
  __shared__ float sF[4]; __shared__ double sD[4]; __shared__ float sMax;
  float* sliceM = (float*)(ws + OFF_SLM);
  double* sliceZ = (double*)(ws + OFF_SLZ);
  int g = blockIdx.x, b = g >> 4, tid = threadIdx.x;
  const float4* l4 = (const float4*)(logits + (size_t)b*Vn + (size_t)(g & 15)*SLN);
  float T = temps[b];
  float m = -3.4e38f;
  for (int j = tid; j < SL4; j += 256){
    float4 v = l4[j];
    m = fmaxf(m, fmaxf(fmaxf(v.x, v.y), fmaxf(v.z, v.w)));
  }
  #pragma unroll
  for (int o = 32; o; o >>= 1) m = fmaxf(m, __shfl_down(m, o));
  if ((tid & 63) == 0) sF[tid >> 6] = m;
  __syncthreads();
  if (tid == 0){ float mm = sF[0]; for (int w = 1; w < 4; ++w) mm = fmaxf(mm, sF[w]); sMax = mm; }
  __syncthreads();
  float a = sMax / T;
  double z = 0.0;
  for (int j = tid; j < SL4; j += 256){
    float4 v = l4[j];
    z += (double)expf(v.x/T - a) + (double)expf(v.y/T - a)
       + (double)expf(v.z/T - a) + (double)expf(v.w/T - a);
  }
  #pragma unroll
  for (int o = 32; o; o >>= 1) z += __shfl_down(z, o);
  if ((tid & 63) == 0) sD[tid >> 6] = z;
  __syncthreads();
  if (tid == 0){
    double zz = 0.0; for (int w = 0; w < 4; ++w) zz += sD[w];
    sliceM[g] = sMax; sliceZ[g] = zz;
  }
}

// ---- B: head = redundant combine; body = K -> Kc + L1 hist ----
__global__ __launch_bounds__(256) void kB(const float* __restrict__ logits,
    const float* __restrict__ temps, char* ws, unsigned* __restrict__ Kc){
  __shared__ double hS[2*NB];
  __shared__ unsigned hC[2*NB];
  __shared__ float sA, sZf;
  float* sliceM = (float*)(ws + OFF_SLM);
  double* sliceZ = (double*)(ws + OFF_SLZ);
  RowWS* rows = (RowWS*)(ws + OFF_ROWS);
  double* L1S = (double*)(ws + OFF_L1S);
  unsigned* L1C = (unsigned*)(ws + OFF_L1C);
  int g = blockIdx.x, b = g >> 4, sl = g & 15, tid = threadIdx.x;
  float T = temps[b];
  if (tid == 0){
    float M = sliceM[b*16];
    for (int s = 1; s < 16; ++s) M = fmaxf(M, sliceM[b*16+s]);
    float A = M / T;
    double Z = 0.0;
    for (int s = 0; s < 16; ++s)
      Z += sliceZ[b*16+s] * exp((double)(sliceM[b*16+s] / T) - (double)A);
    sA = A; sZf = (float)Z;
    if (sl == 0) rows[b].Zf = (float)Z;
  }
  for (int i = tid; i < 2*NB; i += 256){ hS[i] = 0.0; hC[i] = 0u; }
  __syncthreads();
  float A = sA, Zf = sZf;
  size_t base = (size_t)b*Vn + (size_t)sl*SLN;
  const float4* l4 = (const float4*)(logits + base);
  uint4* K4 = (uint4*)(Kc + base);
  int cp = (tid >> 6) & 1;
  for (int j = tid; j < SL4; j += 256){
    float4 v = l4[j];
    uint4 kk;
    float p0 = expf(v.x/T - A) / Zf; kk.x = __float_as_uint(p0);
    float p1 = expf(v.y/T - A) / Zf; kk.y = __float_as_uint(p1);
    float p2 = expf(v.z/T - A) / Zf; kk.z = __float_as_uint(p2);
    float p3 = expf(v.w/T - A) / Zf; kk.w = __float_as_uint(p3);
    unsigned b0 = min(kk.x >> 21, NB-1u), b1 = min(kk.y >> 21, NB-1u);
    unsigned b2 = min(kk.z >> 21, NB-1u), b3 = min(kk.w >> 21, NB-1u);
    unsafeAtomicAdd(&hS[cp*NB + b0], (double)p0); atomicAdd(&hC[cp*NB + b0], 1u);
    unsafeAtomicAdd(&hS[cp*NB + b1], (double)p1); atomicAdd(&hC[cp*NB + b1], 1u);
    unsafeAtomicAdd(&hS[cp*NB + b2], (double)p2); atomicAdd(&hC[cp*NB + b2], 1u);
    unsafeAtomicAdd(&hS[cp*NB + b3], (double)p3); atomicAdd(&hC[cp*NB + b3], 1u);
    K4[j] = kk;
  }
  __syncthreads();
  for (int bin = tid; bin < NB; bin += 256){
    unsigned c = hC[bin] + hC[NB+bin];
    if (c){
      unsafeAtomicAdd(&L1S[(size_t)b*NB + bin], hS[bin] + hS[NB+bin]);
      atomicAdd(&L1C[(size_t)b*NB + bin], c);
    }
  }
}

// ---- C: head = redundant L1 walk; body = L2 hist q0..q3 ----
__global__ __launch_bounds__(256) void kC(const float* __restrict__ temps, char* ws,
    const unsigned* __restrict__ Kc, const int* __restrict__ top_ks,
    const float* __restrict__ top_ps, const float* __restrict__ top_ps2,
    const float* __restrict__ min_ps){
  __shared__ double   hS[4*NB];
  __shared__ unsigned hC[4*NB];
  __shared__ int mx0, mx1, mx2, mnz;
  __shared__ unsigned sCB[4], sCBef[4];
  __shared__ double sSBef[4];
  RowWS* rows = (RowWS*)(ws + OFF_ROWS);
  double* L1S = (double*)(ws + OFF_L1S);
  unsigned* L1C = (unsigned*)(ws + OFF_L1C);
  double* L2S = (double*)(ws + OFF_L2S);
  unsigned* L2C = (unsigned*)(ws + OFF_L2C);
  int g = blockIdx.x, b = g >> 4, sl = g & 15, tid = threadIdx.x;
  // --- head: L1 walk (redundant per block, deterministic) ---
  double* sS = hS; unsigned* sC = hC;
  if (tid == 0){ sS[512] = 0.0; sC[512] = 0u; mx0 = -1; mx1 = -1; mx2 = -1; mnz = NB; }
  unsigned cA = L1C[(size_t)b*NB + tid];
  unsigned cB2 = L1C[(size_t)b*NB + tid + 256];
  double vA = L1S[(size_t)b*NB + tid];
  double vB = L1S[(size_t)b*NB + tid + 256];
  __syncthreads();
  sS[tid] = vA; sS[tid+256] = vB; sC[tid] = cA; sC[tid+256] = cB2;
  __syncthreads();
  scan512(sS, sC);
  float Zf = rows[b].Zf;
  unsigned thrBits = __float_as_uint((1.0f / Zf) * min_ps[b]);
  int thrBin = (int)(thrBits >> 21); if (thrBin > NB-1) thrBin = NB-1;
  unsigned k = (unsigned)top_ks[b];
  double tauP = (double)top_ps[b], tauP2 = (double)top_ps2[b];
  if (cA){
    if (sC[tid] >= k)    atomicMax(&mx0, tid);
    if (sS[tid] > tauP ) atomicMax(&mx1, tid);
    if (sS[tid] > tauP2) atomicMax(&mx2, tid);
    atomicMin(&mnz, tid);
  }
  if (cB2){
    int t2 = tid + 256;
    if (sC[t2] >= k)    atomicMax(&mx0, t2);
    if (sS[t2] > tauP ) atomicMax(&mx1, t2);
    if (sS[t2] > tauP2) atomicMax(&mx2, t2);
    atomicMin(&mnz, t2);
  }
  __syncthreads();
  int w0 = mx0, w1 = (mx1 >= 0) ? mx1 : mnz, w2 = (mx2 >= 0) ? mx2 : mnz;
  #pragma unroll
  for (int h = 0; h < 2; ++h){
    int i = tid + h*256;
    if (i == thrBin){ sCB[3] = (unsigned)i; sCBef[3] = sC[i+1]; sSBef[3] = sS[i+1]; }
    if (i == w0){ sCB[0] = (unsigned)i; sCBef[0] = sC[i+1]; sSBef[0] = sS[i+1]; }
    if (i == w1){ sCB[1] = (unsigned)i; sCBef[1] = sC[i+1]; sSBef[1] = sS[i+1]; }
    if (i == w2){ sCB[2] = (unsigned)i; sCBef[2] = sC[i+1]; sSBef[2] = sS[i+1]; }
  }
  __syncthreads();
  if (sl == 0 && tid < 4){
    rows[b].cutBin[tid] = sCB[tid];
    rows[b].CbefL1[tid] = sCBef[tid];
    rows[b].SbefL1[tid] = sSBef[tid];
  }
  unsigned tb0 = sCB[0], tb1 = sCB[1], tb2 = sCB[2], tb3 = sCB[3];
  __syncthreads();
  // --- body: L2 hist ---
  for (int i = tid; i < 4*NB; i += 256){ hS[i] = 0.0; hC[i] = 0u; }
  __syncthreads();
  const uint4* K4 = (const uint4*)(Kc + (size_t)b*Vn + (size_t)sl*SLN);
  for (int j = tid; j < SL4; j += 256){
    uint4 kk = K4[j];
    #pragma unroll
    for (int c = 0; c < 4; ++c){
      unsigned K = (c==0)?kk.x:(c==1)?kk.y:(c==2)?kk.z:kk.w;
      unsigned bin = K >> 21, sub = (K >> 12) & (NB-1);
      double p = (double)__uint_as_float(K);
      if (bin == tb0){ unsafeAtomicAdd(&hS[0*NB+sub], p); atomicAdd(&hC[0*NB+sub], 1u); }
      if (bin == tb1){ unsafeAtomicAdd(&hS[1*NB+sub], p); atomicAdd(&hC[1*NB+sub], 1u); }
      if (bin == tb2){ unsafeAtomicAdd(&hS[2*NB+sub], p); atomicAdd(&hC[2*NB+sub], 1u); }
      if (bin == tb3){ unsafeAtomicAdd(&hS[3*NB+sub], p); atomicAdd(&hC[3*NB+sub], 1u); }
    }
  }
  __syncthreads();
  for (int i = tid; i < 4*NB; i += 256){
    if (hC[i]){
      unsafeAtomicAdd(&L2S[((size_t)b*4)*NB + i], hS[i]);
      atomicAdd(&L2C[((size_t)b*4)*NB + i], hC[i]);
    }
  }
}

// ---- D: head = redundant 4x L2 walk; body = collect q-lists + superset ----
__global__ __launch_bounds__(256) void kD(char* ws, const unsigned* __restrict__ Kc,
    const int* __restrict__ top_ks, const float* __restrict__ top_ps,
    const float* __restrict__ top_ps2, const float* __restrict__ min_ps){
  __shared__ double sS[513];
  __shared__ unsigned sC[513];
  __shared__ int mx0, mnz;
  __shared__ unsigned sCP[4], sCBef2[4];
  __shared__ double sSBef2[4];
  __shared__ unsigned sSup;
  RowWS* rows = (RowWS*)(ws + OFF_ROWS);
  double* L2S = (double*)(ws + OFF_L2S);
  unsigned* L2C = (unsigned*)(ws + OFF_L2C);
  unsigned* lcnt = (unsigned*)(ws + OFF_LCNT);
  unsigned* skc = (unsigned*)(ws + OFF_SKC);
  unsigned long long* ql = (unsigned long long*)(ws + OFF_QL);
  unsigned long long* SK = (unsigned long long*)(ws + OFF_SK);
  int g = blockIdx.x, b = g >> 4, sl = g & 15, tid = threadIdx.x;
  float Zf = rows[b].Zf;
  unsigned thrBits = __float_as_uint((1.0f / Zf) * min_ps[b]);
  unsigned k = (unsigned)top_ks[b];
  double tauP = (double)top_ps[b], tauP2 = (double)top_ps2[b];
  for (int q = 0; q < 4; ++q){
    if (tid == 0){ sS[512] = 0.0; sC[512] = 0u; mx0 = -1; mnz = NB; }
    unsigned cA = L2C[((size_t)b*4+q)*NB + tid];
    unsigned cB2 = L2C[((size_t)b*4+q)*NB + tid + 256];
    double vA = L2S[((size_t)b*4+q)*NB + tid];
    double vB = L2S[((size_t)b*4+q)*NB + tid + 256];
    __syncthreads();
    sS[tid] = vA; sS[tid+256] = vB; sC[tid] = cA; sC[tid+256] = cB2;
    __syncthreads();
    scan512(sS, sC);
    unsigned baseC = rows[b].CbefL1[q], cutBin = rows[b].cutBin[q];
    double baseS = rows[b].SbefL1[q];
    if (q == 3){
      int thrSub = (int)((thrBits >> 12) & (NB-1));
      #pragma unroll
      for (int h = 0; h < 2; ++h){
        int i = tid + h*256;
        if (i == thrSub){
          sCP[3] = (cutBin << 9) | (unsigned)i;
          sCBef2[3] = baseC + sC[i+1]; sSBef2[3] = baseS + sS[i+1];
        }
      }
    } else {
      double tau = (q == 1) ? tauP : tauP2;
      if (cA){
        if (q == 0){ if (baseC + sC[tid] >= k) atomicMax(&mx0, tid); }
        else       { if (baseS + sS[tid] > tau) atomicMax(&mx0, tid); }
        atomicMin(&mnz, tid);
      }
      if (cB2){
        int t2 = tid + 256;
        if (q == 0){ if (baseC + sC[t2] >= k) atomicMax(&mx0, t2); }
        else       { if (baseS + sS[t2] > tau) atomicMax(&mx0, t2); }
        atomicMin(&mnz, t2);
      }
      __syncthreads();
      int w = (mx0 >= 0) ? mx0 : mnz;
      #pragma unroll
      for (int h = 0; h < 2; ++h){
        int i = tid + h*256;
        if (i == w){
          sCP[q] = (cutBin << 9) | (unsigned)i;
          sCBef2[q] = baseC + sC[i+1]; sSBef2[q] = baseS + sS[i+1];
        }
      }
    }
    __syncthreads();
  }
  if (tid == 0){
    unsigned P = sCP[0];
    if (sCP[1] > P) P = sCP[1];
    if (sCP[3] > P) P = sCP[3];
    sSup = P;
  }
  __syncthreads();
  if (sl == 0){
    if (tid < 4){
      rows[b].cutPre[tid] = sCP[tid];
      rows[b].CbefL2[tid] = sCBef2[tid];
      rows[b].SbefL2[tid] = sSBef2[tid];
    }
    if (tid == 4) rows[b].supP = sSup;
  }
  // --- body: collect ---
  unsigned t0 = sCP[0], t1 = sCP[1], t2 = sCP[2], t3 = sCP[3], P = sSup;
  int ibase = sl*SLN;
  const uint4* K4 = (const uint4*)(Kc + (size_t)b*Vn + ibase);
  for (int j = tid; j < SL4; j += 256){
    uint4 kk = K4[j];
    #pragma unroll
    for (int c = 0; c < 4; ++c){
      unsigned K = (c==0)?kk.x:(c==1)?kk.y:(c==2)?kk.z:kk.w;
      unsigned pre = K >> 12;
      if (pre < P && pre != t0 && pre != t1 && pre != t2 && pre != t3) continue;
      int i = ibase + j*4 + c;
      unsigned long long e = (((unsigned long long)(~K)) << 32) | (unsigned)i;
      if (pre == t0){ unsigned pos = atomicAdd(&lcnt[b*4+0], 1u); if (pos < CAPQ) ql[((size_t)b*4+0)*CAPQ+pos] = e; }
      if (pre == t1){ unsigned pos = atomicAdd(&lcnt[b*4+1], 1u); if (pos < CAPQ) ql[((size_t)b*4+1)*CAPQ+pos] = e; }
      if (pre == t2){ unsigned pos = atomicAdd(&lcnt[b*4+2], 1u); if (pos < CAPQ) ql[((size_t)b*4+2)*CAPQ+pos] = e; }
      if (pre == t3){ unsigned pos = atomicAdd(&lcnt[b*4+3], 1u); if (pos < CAPQ) ql[((size_t)b*4+3)*CAPQ+pos] = e; }
      if (pre >= P){ unsigned pos = atomicAdd(&skc[b], 1u); if (pos < SKCAP) SK[(size_t)b*SKCAP+pos] = e; }
    }
  }
}

// ---- E: per-row resolve + sample (128 blocks, all-parallel sorts) ----
__global__ __launch_bounds__(256) void kE(char* ws,
    const int* __restrict__ top_ks, const float* __restrict__ top_ps,
    const float* __restrict__ top_ps2, const float* __restrict__ min_ps,
    const float* __restrict__ uarr,
    float* __restrict__ outTok, float* __restrict__ outNtlp){
  __shared__ unsigned long long sLsQ[4*CAPQ];   // 16 KB
  __shared__ unsigned long long sSKL[4096];     // 32 KB
  __shared__ double sCh[256];
  __shared__ int sPos, sP2;
  __shared__ unsigned sV0, sV2;
  __shared__ int sI0, sI2;
  __shared__ float sS2f;
  __shared__ double sT4d;
  RowWS* rows = (RowWS*)(ws + OFF_ROWS);
  unsigned* lcnt = (unsigned*)(ws + OFF_LCNT);
  unsigned* skc = (unsigned*)(ws + OFF_SKC);
  unsigned long long* ql = (unsigned long long*)(ws + OFF_QL);
  unsigned long long* SK = (unsigned long long*)(ws + OFF_SK);
  int b = blockIdx.x, tid = threadIdx.x;
  RowWS& R = rows[b];
  int nq[4];
  for (int q = 0; q < 4; ++q){
    int n = (int)lcnt[b*4+q]; if (n > CAPQ) n = CAPQ; nq[q] = n;
    for (int j = tid; j < CAPQ; j += 256)
      sLsQ[q*CAPQ+j] = (j < n) ? ql[((size_t)b*4+q)*CAPQ + j] : 0xFFFFFFFFFFFFFFFFull;
  }
  int nsk = (int)skc[b]; if (nsk > SKCAP) nsk = SKCAP;
  for (int j = tid; j < 4096; j += 256)
    sSKL[j] = (j < nsk) ? SK[(size_t)b*SKCAP + j] : 0xFFFFFFFFFFFFFFFFull;
  if (tid == 0){
    int p2 = 2; while (p2 < nsk) p2 <<= 1;
    sP2 = p2; sPos = 0x7FFFFFFF;
  }
  __syncthreads();
  // parallel bitonic: 4 independent 512-segments (ascending each)
  for (unsigned kk2 = 2; kk2 <= 512u; kk2 <<= 1){
    for (unsigned jj = kk2 >> 1; jj > 0; jj >>= 1){
      for (int i = tid; i < 4*CAPQ; i += 256){
        int il = i & 511, seg = i >> 9;
        int jx = il ^ (int)jj;
        if (jx > il){
          int a = seg*512 + il, b2 = seg*512 + jx;
          unsigned long long x = sLsQ[a], y = sLsQ[b2];
          bool up = ((il & kk2) == 0);
          if ((x > y) == up){ sLsQ[a] = y; sLsQ[b2] = x; }
        }
      }
      __syncthreads();
    }
  }
  // superset bitonic (P2 <= 4096, ascending)
  int P2 = sP2;
  for (unsigned kk2 = 2; kk2 <= (unsigned)P2; kk2 <<= 1){
    for (unsigned jj = kk2 >> 1; jj > 0; jj >>= 1){
      for (int i = tid; i < P2; i += 256){
        int ixj = i ^ (int)jj;
        if (ixj > i){
          unsigned long long x = sSKL[i], y = sSKL[ixj];
          bool up = ((i & kk2) == 0);
          if ((x > y) == up){ sSKL[i] = y; sSKL[ixj] = x; }
        }
      }
      __syncthreads();
    }
  }
  // thread-0 boundary resolution (short linear scans over sorted lists)
  if (tid == 0){
    int k = top_ks[b];
    double tauP = (double)top_ps[b], tauP2 = (double)top_ps2[b];
    float Zf = R.Zf;
    unsigned thrB = __float_as_uint((1.0f / Zf) * min_ps[b]);
    unsigned vS[4]; int iS[4]; double sk[4];
    for (int q = 0; q < 4; ++q){
      int n = nq[q];
      unsigned long long* L = &sLsQ[q*CAPQ];
      double S = R.SbefL2[q];
      if (q == 0){
        if (n > 0){
          int mm = k - (int)R.CbefL2[0]; if (mm < 1) mm = 1; if (mm > n) mm = n;
          for (int j = 0; j < mm; ++j){ unsigned K = ~(unsigned)(L[j] >> 32); S += (double)__uint_as_float(K); }
          unsigned long long e = L[mm-1];
          vS[0] = ~(unsigned)(e >> 32); iS[0] = (int)(unsigned)(e & 0xFFFFFFFFu); sk[0] = S;
        } else { vS[0] = 0u; iS[0] = 0x7FFFFFFF; sk[0] = S; }
      } else if (q < 3){
        double tau = (q == 1) ? tauP : tauP2;
        int last = -1;
        for (int j = 0; j < n; ++j){
          if (S > tau) break;
          unsigned K = ~(unsigned)(L[j] >> 32);
          S += (double)__uint_as_float(K); last = j;
        }
        if (n > 0){
          int pick = (last < 0) ? 0 : last;
          unsigned long long e = L[pick];
          vS[q] = ~(unsigned)(e >> 32); iS[q] = (int)(unsigned)(e & 0xFFFFFFFFu); sk[q] = S;
        } else { vS[q] = 0u; iS[q] = 0x7FFFFFFF; sk[q] = S; }
      } else {
        for (int j = 0; j < n; ++j){
          unsigned K = ~(unsigned)(L[j] >> 32);
          if (K < thrB) break;
          S += (double)__uint_as_float(K);
        }
        vS[3] = thrB; iS[3] = 0x7FFFFFFF; sk[3] = S;
      }
    }
    unsigned v0 = vS[0]; int i0 = iS[0]; double tot = sk[0];
    if (vS[1] > v0 || (vS[1] == v0 && iS[1] < i0)){ v0 = vS[1]; i0 = iS[1]; tot = sk[1]; }
    if (vS[3] > v0 || (vS[3] == v0 && iS[3] < i0)){ v0 = vS[3]; i0 = iS[3]; tot = sk[3]; }
    sV0 = v0; sI0 = i0;
    sV2 = vS[2]; sI2 = iS[2]; sS2f = (float)sk[2];
    R.v2 = vS[2]; R.i2 = iS[2]; R.S2f = (float)sk[2];
    sT4d = (double)(uarr[b] * (float)tot);
  }
  __syncthreads();
  // chunked f64 CDF over sorted kept elements; first run >= t4
  {
    unsigned v0 = sV0; int i0 = sI0; double t4d = sT4d;
    int c0 = tid * 16;
    double loc = 0.0;
    #pragma unroll
    for (int ii = 0; ii < 16; ++ii){
      unsigned long long e = sSKL[c0+ii];
      unsigned K = ~(unsigned)(e >> 32); int idx = (int)(unsigned)(e & 0xFFFFFFFFu);
      bool kept = (K > v0) || (K == v0 && idx <= i0);
      if (kept) loc += (double)__uint_as_float(K);
    }
    sCh[tid] = loc;
    __syncthreads();
    for (int off = 1; off < 256; off <<= 1){
      double v = sCh[tid] + ((tid >= off) ? sCh[tid-off] : 0.0);
      __syncthreads(); sCh[tid] = v; __syncthreads();
    }
    double run = sCh[tid] - loc;   // exclusive base
    for (int ii = 0; ii < 16; ++ii){
      unsigned long long e = sSKL[c0+ii];
      unsigned K = ~(unsigned)(e >> 32); int idx = (int)(unsigned)(e & 0xFFFFFFFFu);
      bool kept = (K > v0) || (K == v0 && idx <= i0);
      if (kept) run += (double)__uint_as_float(K);
      if (run >= t4d){ atomicMin(&sPos, c0+ii); break; }
    }
  }
  __syncthreads();
  if (tid == 0){
    int token; unsigned pB;
    if (sPos == 0x7FFFFFFF){ token = sI0; pB = sV0; }
    else {
      unsigned long long e = sSKL[sPos];
      pB = ~(unsigned)(e >> 32); token = (int)(unsigned)(e & 0xFFFFFFFFu);
    }
    unsigned v2 = sV2; int i2 = sI2;
    bool kept2 = (pB > v2) || (pB == v2 && token <= i2);
    float pt = __uint_as_float(pB);
    float lp = kept2 ? fmaxf(logf(pt / sS2f), FMINV) : FOUT;
    outTok[b] = (float)token;
    outNtlp[b] = lp;
  }
}

// ---- F: logprobs write (in place over Kc) ----
__global__ __launch_bounds__(256) void kF(const char* __restrict__ ws, float* __restrict__ outLp){
  const RowWS* rows = (const RowWS*)(ws + OFF_ROWS);
  int g = blockIdx.x, b = g >> 4, sl = g & 15, tid = threadIdx.x;
  unsigned v2 = rows[b].v2; int i2 = rows[b].i2; float S2f = rows[b].S2f;
  int ibase = sl*SLN;
  float4* O4 = (float4*)(outLp + (size_t)b*Vn + ibase);
  const uint4* K4 = (const uint4*)O4;
  for (int j = tid; j < SL4; j += 256){
    uint4 kk = K4[j];
    float4 o;
    #pragma unroll
    for (int c = 0; c < 4; ++c){
      unsigned K = (c==0)?kk.x:(c==1)?kk.y:(c==2)?kk.z:kk.w;
      int i = ibase + j*4 + c;
      float p = __uint_as_float(K);
      float val = (K > v2 || (K == v2 && i <= i2)) ? fmaxf(logf(p / S2f), FMINV) : FOUT;
      if (c==0) o.x = val; else if (c==1) o.y = val; else if (c==2) o.z = val; else o.w = val;
    }
    O4[j] = o;
  }
}

extern "C" void kernel_launch(void* const* d_in, const int* in_sizes, int n_in,
                              void* d_out, int out_size, void* d_ws, size_t ws_size,
                              hipStream_t stream)
{
  const float* logits  = (const float*)d_in[0];
  const float* temps   = (const float*)d_in[1];
  const int*   top_ks  = (const int*)d_in[2];
  const float* top_ps  = (const float*)d_in[3];
  const float* top_ps2 = (const float*)d_in[4];
  const float* min_ps  = (const float*)d_in[5];
  const float* uarr    = (const float*)d_in[6];

  float* outTok  = (float*)d_out;
  float* outLp   = outTok + Bn;
  float* outNtlp = outLp + (size_t)Bn * Vn;
  unsigned* Kc   = (unsigned*)outLp;       // K-cache lives in the output buffer

  char* ws = (char*)d_ws;
  hipMemsetAsync(ws + ZSTART, 0, ZBYTES, stream);
  const int G = Bn * SLICES;   // 2048
  kA<<<G,  256, 0, stream>>>(logits, temps, ws);
  kB<<<G,  256, 0, stream>>>(logits, temps, ws, Kc);
  kC<<<G,  256, 0, stream>>>(temps, ws, Kc, top_ks, top_ps, top_ps2, min_ps);
  kD<<<G,  256, 0, stream>>>(ws, Kc, top_ks, top_ps, top_ps2, min_ps);
  kE<<<Bn, 256, 0, stream>>>(ws, top_ks, top_ps, top_ps2, min_ps, uarr, outTok, outNtlp);
  kF<<<G,  256, 0, stream>>>(ws, outLp);
}